// Round 1
// baseline (13.806 us; speedup 1.0000x reference)
//
#include <hip/hip_runtime.h>
#include <stdint.h>

#define M_MACH 50
#define N_JOBS 100
#define MT_BITS 4
#define JS_BITS 2
#define NFEAT (M_MACH * MT_BITS + N_JOBS * JS_BITS + M_MACH * N_JOBS) // 5400
#define A_DIM 32
#define C_DIM 1000
#define INIT_T 16

// Kernel 1: encode state -> feats[5400] (uint8 0/1) in workspace; zero d_out.
__global__ void encode_kernel(const float* __restrict__ state,
                              uint8_t* __restrict__ feats,
                              float* __restrict__ out) {
    const int tid = threadIdx.x;

    if (tid < A_DIM) out[tid] = 0.0f;

    __shared__ float smax;
    if (tid < 64) {
        float v = (tid < M_MACH) ? state[tid] : -1.0f;
        #pragma unroll
        for (int off = 32; off > 0; off >>= 1)
            v = fmaxf(v, __shfl_down(v, off, 64));
        if (tid == 0) smax = v;
    }
    __syncthreads();
    const float mx = smax;

    for (int f = tid; f < NFEAT; f += blockDim.x) {
        uint8_t bit;
        if (f < M_MACH * MT_BITS) {
            // machine-time bits: feature i*4+k = (norm_i >> k) & 1
            const int i = f >> 2;
            const int k = f & 3;
            int norm = 0;
            if (mx > 0.0f) {
                // match JAX f32 math: (mt / safe_mx) * 15, truncate toward 0
                norm = (int)((state[i] / mx) * 15.0f);
            }
            bit = (uint8_t)((norm >> k) & 1);
        } else if (f < M_MACH * MT_BITS + N_JOBS * JS_BITS) {
            const int rel = f - M_MACH * MT_BITS;
            const int j = rel >> 1;
            const int k = rel & 1;
            int status = (int)(state[M_MACH + j] * 3.0f);
            if (status > 3) status = 3;
            bit = (uint8_t)((status >> k) & 1);
        } else {
            const int i = f - (M_MACH * MT_BITS + N_JOBS * JS_BITS);
            bit = (uint8_t)((int)state[M_MACH + N_JOBS + i]);
        }
        feats[f] = bit;
    }
}

// Kernel 2: one wave per clause, early-exit any() scan.
// violation[a,c] = any_f( ta[a][c][feats[f]][f] > INIT )
__global__ __launch_bounds__(256) void clause_kernel(
    const int8_t* __restrict__ ta,
    const int8_t* __restrict__ sign,
    const uint8_t* __restrict__ feats,
    float* __restrict__ out) {
    const int lane = threadIdx.x & 63;
    const int wid  = threadIdx.x >> 6;
    const int gwave = blockIdx.x * 4 + wid;
    const int nwaves = gridDim.x * 4;

    for (int q = gwave; q < A_DIM * C_DIM; q += nwaves) {
        const int a = q / C_DIM;
        const int8_t* base = ta + (size_t)q * (2 * NFEAT);

        bool violated = false;
        for (int f0 = 0; f0 < NFEAT; f0 += 64) {
            const int f = f0 + lane;
            bool v = false;
            if (f < NFEAT) {
                const int p = feats[f];               // 0 or 1 -> plane select
                v = base[p * NFEAT + f] > INIT_T;
            }
            if (__any(v)) { violated = true; break; }
        }

        if (!violated && lane == 0) {
            atomicAdd(&out[a], (float)sign[q]);
        }
    }
}

extern "C" void kernel_launch(void* const* d_in, const int* in_sizes, int n_in,
                              void* d_out, int out_size, void* d_ws, size_t ws_size,
                              hipStream_t stream) {
    const float*  state = (const float*)d_in[0];
    const int8_t* ta    = (const int8_t*)d_in[1];
    const int8_t* sign  = (const int8_t*)d_in[2];
    float* out = (float*)d_out;
    uint8_t* feats = (uint8_t*)d_ws;

    encode_kernel<<<1, 256, 0, stream>>>(state, feats, out);

    // 2048 blocks x 4 waves = 8192 waves; each handles ~4 clauses (grid-stride).
    clause_kernel<<<2048, 256, 0, stream>>>(ta, sign, feats, out);
}